// Round 1
// baseline (190.842 us; speedup 1.0000x reference)
//
#include <hip/hip_runtime.h>

// Problem constants (fixed shapes from setup_inputs / PROJECT_CFG)
#define BB   2
#define CC   32
#define HH   32
#define WW   256
#define NN   (HH * WW)          // 8192 points per batch
#define NXv  440
#define NYv  500
#define NVOXv (NXv * NYv)       // 220000

#define TILE  2048              // candidate tile staged in LDS (32 KB)
#define SPLIT 8                 // threads per far point
#define FPB   32                // far points per 256-thread block

#define INSERT3(dd, jj)                                            \
    if ((dd) < d2) {                                               \
        if ((dd) < d1) {                                           \
            d2 = d1; i2 = i1;                                      \
            if ((dd) < d0) { d1 = d0; i1 = i0; d0 = (dd); i0 = (jj); } \
            else           { d1 = (dd); i1 = (jj); }               \
        } else { d2 = (dd); i2 = (jj); }                           \
    }

// ---------------------------------------------------------------------------
// Kernel 1: near points — compact valid candidates, scatter feats + counts
// ---------------------------------------------------------------------------
__global__ __launch_bounds__(256) void k_near(
    const float* __restrict__ fv,    // (B,C,H,W)
    const float* __restrict__ pim,   // (B,4,H,W)
    const int*   __restrict__ pm,    // (B,H,W)
    float*       __restrict__ out,   // (B,C,NY,NX)
    int*         __restrict__ cnt,   // (B,NVOX)
    float4*      __restrict__ cand,  // (B,N)
    int*         __restrict__ ccnt)  // (B)
{
    int b = blockIdx.y;
    int i = blockIdx.x * blockDim.x + threadIdx.x;
    if (i >= NN) return;
    if (pm[b * NN + i] <= 0) return;

    float x = pim[(b * 4 + 0) * NN + i];
    float y = pim[(b * 4 + 1) * NN + i];
    float z = pim[(b * 4 + 2) * NN + i];

    // append to candidate list (order-independent downstream)
    int pos = atomicAdd(&ccnt[b], 1);
    cand[b * NN + pos] = make_float4(x, y, z, __int_as_float(i));

    // BEV scatter (m & in-bounds)
    int ix = (int)floorf((x - 0.0f)  / 0.16f);
    int iy = (int)floorf((y + 40.0f) / 0.16f);
    if (ix < 0 || ix >= NXv || iy < 0 || iy >= NYv) return;
    if (!(z >= -3.0f && z < 1.0f)) return;
    int vox = iy * NXv + ix;
    atomicAdd(&cnt[b * NVOXv + vox], 1);

    const float* fvb  = fv  + (size_t)b * CC * NN + i;
    float*       outb = out + (size_t)b * CC * NVOXv + vox;
#pragma unroll
    for (int c = 0; c < CC; ++c)
        atomicAdd(outb + c * NVOXv, fvb[c * NN]);
}

// ---------------------------------------------------------------------------
// Kernel 2: far points — 3-NN over candidates, interpolate, scatter
// ---------------------------------------------------------------------------
__global__ __launch_bounds__(256) void k_far(
    const float*  __restrict__ fv,    // (B,C,H,W)
    const float*  __restrict__ pimf,  // (B,4,H,W)
    const int*    __restrict__ pmf,   // (B,H,W)
    const float4* __restrict__ cand,  // (B,N)
    const int*    __restrict__ ccnt,  // (B)
    float*        __restrict__ out,   // (B,C,NY,NX)
    int*          __restrict__ cnt)   // (B,NVOX)
{
    __shared__ float4 sc[TILE];
    int b   = blockIdx.y;
    int tid = threadIdx.x;
    int sub = tid & (SPLIT - 1);      // 0..7 within far-point group (same wave)
    int fp  = tid >> 3;               // 0..31 far point within block
    int j   = blockIdx.x * FPB + fp;

    float x = pimf[(b * 4 + 0) * NN + j];
    float y = pimf[(b * 4 + 1) * NN + j];
    float z = pimf[(b * 4 + 2) * NN + j];

    int ix = (int)floorf((x - 0.0f)  / 0.16f);
    int iy = (int)floorf((y + 40.0f) / 0.16f);
    bool inb = (ix >= 0) && (ix < NXv) && (iy >= 0) && (iy < NYv) &&
               (z >= -3.0f) && (z < 1.0f);
    bool active = (pmf[b * NN + j] > 0) && inb;  // dropped points never reach output

    int nc = ccnt[b];

    float d0 = __builtin_inff(), d1 = __builtin_inff(), d2 = __builtin_inff();
    int   i0 = 0, i1 = 0, i2 = 0;

    for (int t0 = 0; t0 < nc; t0 += TILE) {
        int tn = min(TILE, nc - t0);
        __syncthreads();              // previous tile fully consumed
        for (int k = tid; k < tn; k += 256)
            sc[k] = cand[b * NN + t0 + k];
        __syncthreads();
        if (active) {
            for (int k = sub; k < tn; k += SPLIT) {
                float4 p = sc[k];
                float dx = x - p.x, dy = y - p.y, dz = z - p.z;
                float d  = dx * dx + dy * dy + dz * dz;
                int   ii = __float_as_int(p.w);
                INSERT3(d, ii);
            }
        }
    }

    // butterfly merge of per-thread top-3 across the 8-lane group (same wave)
#pragma unroll
    for (int off = 1; off < SPLIT; off <<= 1) {
        float e0 = __shfl_xor(d0, off), e1 = __shfl_xor(d1, off), e2 = __shfl_xor(d2, off);
        int   g0 = __shfl_xor(i0, off), g1 = __shfl_xor(i1, off), g2 = __shfl_xor(i2, off);
        INSERT3(e0, g0);
        INSERT3(e1, g1);
        INSERT3(e2, g2);
    }

    if (active) {
        float r0 = 1.0f / (d0 + 1e-8f);
        float r1 = 1.0f / (d1 + 1e-8f);
        float r2 = 1.0f / (d2 + 1e-8f);
        float s  = r0 + r1 + r2;
        float w0 = r0 / s, w1 = r1 / s, w2 = r2 / s;

        int vox = iy * NXv + ix;
        if (sub == 0) atomicAdd(&cnt[b * NVOXv + vox], 1);

        const float* fvb  = fv  + (size_t)b * CC * NN;
        float*       outb = out + (size_t)b * CC * NVOXv + vox;
#pragma unroll
        for (int c4 = 0; c4 < CC / SPLIT; ++c4) {
            int c = sub * (CC / SPLIT) + c4;
            float v = w0 * fvb[c * NN + i0] +
                      w1 * fvb[c * NN + i1] +
                      w2 * fvb[c * NN + i2];
            atomicAdd(outb + c * NVOXv, v);
        }
    }
}

// ---------------------------------------------------------------------------
// Kernel 3: finalize mean (divide only where cnt > 1)
// ---------------------------------------------------------------------------
__global__ __launch_bounds__(256) void k_mean(
    float* __restrict__ out, const int* __restrict__ cnt)
{
    int v = blockIdx.x * blockDim.x + threadIdx.x;
    if (v >= NVOXv) return;
    int b = blockIdx.y;
    int c0 = cnt[b * NVOXv + v];
    if (c0 > 1) {
        float cf = (float)c0;
        float* o = out + (size_t)b * CC * NVOXv + v;
#pragma unroll
        for (int c = 0; c < CC; ++c)
            o[c * NVOXv] = o[c * NVOXv] / cf;
    }
}

// ---------------------------------------------------------------------------
extern "C" void kernel_launch(void* const* d_in, const int* in_sizes, int n_in,
                              void* d_out, int out_size, void* d_ws, size_t ws_size,
                              hipStream_t stream)
{
    const float* fv   = (const float*)d_in[0];
    const float* pim  = (const float*)d_in[1];
    const float* pimf = (const float*)d_in[2];
    const int*   pm   = (const int*)d_in[3];
    const int*   pmf  = (const int*)d_in[4];
    float* out = (float*)d_out;

    // ws layout: [ccnt: B ints (padded to 16B)] [cnt: B*NVOX ints] [cand: B*N float4]
    char* ws = (char*)d_ws;
    int*    ccnt = (int*)ws;
    int*    cnt  = (int*)(ws + 16);
    float4* cand = (float4*)(ws + 16 + (size_t)BB * NVOXv * sizeof(int));

    // zero output + counters (graph-capture-safe)
    hipMemsetAsync(d_out, 0, (size_t)out_size * sizeof(float), stream);
    hipMemsetAsync(d_ws, 0, 16 + (size_t)BB * NVOXv * sizeof(int), stream);

    dim3 blk(256);
    dim3 g1((NN + 255) / 256, BB);
    k_near<<<g1, blk, 0, stream>>>(fv, pim, pm, out, cnt, cand, ccnt);

    dim3 g2(NN / FPB, BB);
    k_far<<<g2, blk, 0, stream>>>(fv, pimf, pmf, cand, ccnt, out, cnt);

    dim3 g3((NVOXv + 255) / 256, BB);
    k_mean<<<g3, blk, 0, stream>>>(out, cnt);
}

// Round 2
// 157.988 us; speedup vs baseline: 1.2080x; 1.2080x over previous
//
#include <hip/hip_runtime.h>

// Problem constants (fixed shapes from setup_inputs / PROJECT_CFG)
#define BB   2
#define CC   32
#define NN   8192               // H*W points per batch
#define NXv  440
#define NYv  500
#define NVOXv (NXv * NYv)       // 220000

#define SPLIT 32                // lanes per far point
#define FPB   8                 // far points per 256-thread block

#define INSERT3(dd, jj)                                            \
    if ((dd) < d2) {                                               \
        if ((dd) < d1) {                                           \
            d2 = d1; i2 = i1;                                      \
            if ((dd) < d0) { d1 = d0; i1 = i0; d0 = (dd); i0 = (jj); } \
            else           { d1 = (dd); i1 = (jj); }               \
        } else { d2 = (dd); i2 = (jj); }                           \
    }

// ---------------------------------------------------------------------------
// fv (B,C,N) -> fvT (B,N,C)   [FAST tier only]
// ---------------------------------------------------------------------------
__global__ __launch_bounds__(256) void k_tr(
    const float* __restrict__ fv, float* __restrict__ fvT)
{
    __shared__ float tile[CC][64 + 1];
    int b  = blockIdx.y;
    int i0 = blockIdx.x * 64;
    int t  = threadIdx.x;
    const float* f = fv + (size_t)b * CC * NN;

    int il = t & 63, cb = t >> 6;            // cb 0..3
#pragma unroll
    for (int p = 0; p < 8; ++p) {
        int c = cb + p * 4;
        tile[c][il] = f[(size_t)c * NN + i0 + il];
    }
    __syncthreads();
    float* o = fvT + ((size_t)b * NN + i0) * CC;
    int c2 = t & 31, ib = t >> 5;            // ib 0..7
#pragma unroll
    for (int p = 0; p < 8; ++p) {
        int il2 = ib + p * 8;
        o[(size_t)il2 * CC + c2] = tile[c2][il2];
    }
}

// ---------------------------------------------------------------------------
// Kernel 1: compact near candidates + far actives, scatter near feats/counts
// ---------------------------------------------------------------------------
template <bool FAST>
__global__ __launch_bounds__(256) void k_prep(
    const float* __restrict__ fv,    // (B,C,N)
    const float* __restrict__ fvT,   // (B,N,C)   FAST only
    const float* __restrict__ pim,   // (B,4,N)
    const float* __restrict__ pimf,  // (B,4,N)
    const int*   __restrict__ pm,    // (B,N)
    const int*   __restrict__ pmf,   // (B,N)
    float*       __restrict__ dst,   // FAST: acc (B,NVOX,C) ; slow: out (B,C,NVOX)
    int*         __restrict__ cnt,   // (B,NVOX)
    float4*      __restrict__ cand,  // (B,N)
    int*         __restrict__ ccnt,  // (B)
    float4*      __restrict__ fcand, // (B,N)
    int*         __restrict__ fcnt)  // (B)
{
    int b = blockIdx.y;
    int i = blockIdx.x * blockDim.x + threadIdx.x;

    // ---- far point: compact (pmf>0 && in-bounds); store vox in .w ----
    {
        float x = pimf[(b * 4 + 0) * NN + i];
        float y = pimf[(b * 4 + 1) * NN + i];
        float z = pimf[(b * 4 + 2) * NN + i];
        if (pmf[b * NN + i] > 0) {
            int ix = (int)floorf((x - 0.0f)  / 0.16f);
            int iy = (int)floorf((y + 40.0f) / 0.16f);
            if (ix >= 0 && ix < NXv && iy >= 0 && iy < NYv &&
                z >= -3.0f && z < 1.0f) {
                int vox = iy * NXv + ix;
                int pos = atomicAdd(&fcnt[b], 1);
                fcand[b * NN + pos] = make_float4(x, y, z, __int_as_float(vox));
            }
        }
    }

    // ---- near point: candidate list (mask only) + BEV scatter (mask&inb) ----
    if (pm[b * NN + i] > 0) {
        float x = pim[(b * 4 + 0) * NN + i];
        float y = pim[(b * 4 + 1) * NN + i];
        float z = pim[(b * 4 + 2) * NN + i];
        int pos = atomicAdd(&ccnt[b], 1);
        cand[b * NN + pos] = make_float4(x, y, z, __int_as_float(i));

        int ix = (int)floorf((x - 0.0f)  / 0.16f);
        int iy = (int)floorf((y + 40.0f) / 0.16f);
        if (ix < 0 || ix >= NXv || iy < 0 || iy >= NYv) return;
        if (!(z >= -3.0f && z < 1.0f)) return;
        int vox = iy * NXv + ix;
        atomicAdd(&cnt[b * NVOXv + vox], 1);

        if (FAST) {
            const float* src = fvT + ((size_t)b * NN + i) * CC;
            float*       d   = dst + ((size_t)(b * NVOXv + vox)) * CC;
#pragma unroll
            for (int c = 0; c < CC; ++c)
                atomicAdd(d + c, src[c]);
        } else {
            const float* src = fv + (size_t)b * CC * NN + i;
            float*       d   = dst + (size_t)b * CC * NVOXv + vox;
#pragma unroll
            for (int c = 0; c < CC; ++c)
                atomicAdd(d + (size_t)c * NVOXv, src[(size_t)c * NN]);
        }
    }
}

// ---------------------------------------------------------------------------
// Kernel 2: far 3-NN + interpolate + scatter.  32 lanes per far point.
// ---------------------------------------------------------------------------
template <bool FAST>
__global__ __launch_bounds__(256) void k_far(
    const float*  __restrict__ fv,
    const float*  __restrict__ fvT,
    const float4* __restrict__ cand,
    const int*    __restrict__ ccnt,
    const float4* __restrict__ fcand,
    const int*    __restrict__ fcnt,
    float*        __restrict__ dst,   // FAST: acc ; slow: out
    int*          __restrict__ cnt)
{
    int b  = blockIdx.y;
    int nf = fcnt[b];
    int e0 = blockIdx.x * FPB;
    if (e0 >= nf) return;

    int tid = threadIdx.x;
    int sub = tid & (SPLIT - 1);
    int e   = e0 + (tid >> 5);
    bool active = (e < nf);              // uniform within each 32-lane group
    if (!active) return;

    float4 fp = fcand[b * NN + e];
    float x = fp.x, y = fp.y, z = fp.z;
    int vox = __float_as_int(fp.w);

    int nc = ccnt[b];
    const float4* cb = cand + b * NN;

    float d0 = __builtin_inff(), d1 = __builtin_inff(), d2 = __builtin_inff();
    int   i0 = 0, i1 = 0, i2 = 0;

    int k = sub;
    for (; k + 96 < nc; k += 128) {
        float4 pa = cb[k];
        float4 pb = cb[k + 32];
        float4 pc = cb[k + 64];
        float4 pd = cb[k + 96];
        float dxa = x - pa.x, dya = y - pa.y, dza = z - pa.z;
        float dxb = x - pb.x, dyb = y - pb.y, dzb = z - pb.z;
        float dxc = x - pc.x, dyc = y - pc.y, dzc = z - pc.z;
        float dxd = x - pd.x, dyd = y - pd.y, dzd = z - pd.z;
        float da = dxa * dxa + dya * dya + dza * dza;
        float db = dxb * dxb + dyb * dyb + dzb * dzb;
        float dc = dxc * dxc + dyc * dyc + dzc * dzc;
        float dd = dxd * dxd + dyd * dyd + dzd * dzd;
        int ia = __float_as_int(pa.w);
        int ib = __float_as_int(pb.w);
        int ic = __float_as_int(pc.w);
        int id = __float_as_int(pd.w);
        INSERT3(da, ia);
        INSERT3(db, ib);
        INSERT3(dc, ic);
        INSERT3(dd, id);
    }
    for (; k < nc; k += SPLIT) {
        float4 p = cb[k];
        float dx = x - p.x, dy = y - p.y, dz = z - p.z;
        float d  = dx * dx + dy * dy + dz * dz;
        int  ii  = __float_as_int(p.w);
        INSERT3(d, ii);
    }

    // butterfly merge across the 32-lane group
#pragma unroll
    for (int off = 1; off < SPLIT; off <<= 1) {
        float m0 = __shfl_xor(d0, off), m1 = __shfl_xor(d1, off), m2 = __shfl_xor(d2, off);
        int   g0 = __shfl_xor(i0, off), g1 = __shfl_xor(i1, off), g2 = __shfl_xor(i2, off);
        INSERT3(m0, g0);
        INSERT3(m1, g1);
        INSERT3(m2, g2);
    }

    float r0 = 1.0f / (d0 + 1e-8f);
    float r1 = 1.0f / (d1 + 1e-8f);
    float r2 = 1.0f / (d2 + 1e-8f);
    float s  = r0 + r1 + r2;
    float w0 = r0 / s, w1 = r1 / s, w2 = r2 / s;

    if (sub == 0) atomicAdd(&cnt[b * NVOXv + vox], 1);

    if (FAST) {
        const float* fb = fvT + (size_t)b * NN * CC;
        float v = w0 * fb[((size_t)i0 << 5) + sub] +
                  w1 * fb[((size_t)i1 << 5) + sub] +
                  w2 * fb[((size_t)i2 << 5) + sub];
        atomicAdd(dst + (((size_t)(b * NVOXv + vox)) << 5) + sub, v);
    } else {
        const float* fb = fv + (size_t)b * CC * NN;
        float v = w0 * fb[(size_t)sub * NN + i0] +
                  w1 * fb[(size_t)sub * NN + i1] +
                  w2 * fb[(size_t)sub * NN + i2];
        atomicAdd(dst + (size_t)b * CC * NVOXv + (size_t)sub * NVOXv + vox, v);
    }
}

// ---------------------------------------------------------------------------
// Kernel 3 (FAST): acc (B,NVOX,C) / max(cnt,1) -> out (B,C,NVOX), transposed
// ---------------------------------------------------------------------------
__global__ __launch_bounds__(256) void k_mean_fast(
    const float* __restrict__ acc, const int* __restrict__ cnt,
    float* __restrict__ out)
{
    __shared__ float tile[CC][64 + 1];
    int b  = blockIdx.y;
    int v0 = blockIdx.x * 64;
    int t  = threadIdx.x;

    int vl = t >> 2, cq = (t & 3) * 8;       // 4 threads per voxel, 8 ch each
    int v  = v0 + vl;
    float vals[8];
    if (v < NVOXv) {
        float cf = (float)max(cnt[b * NVOXv + v], 1);
        const float* a = acc + (((size_t)(b * NVOXv + v)) << 5) + cq;
        float4 a0 = *(const float4*)(a);
        float4 a1 = *(const float4*)(a + 4);
        vals[0] = a0.x / cf; vals[1] = a0.y / cf; vals[2] = a0.z / cf; vals[3] = a0.w / cf;
        vals[4] = a1.x / cf; vals[5] = a1.y / cf; vals[6] = a1.z / cf; vals[7] = a1.w / cf;
    } else {
#pragma unroll
        for (int u = 0; u < 8; ++u) vals[u] = 0.0f;
    }
#pragma unroll
    for (int u = 0; u < 8; ++u) tile[cq + u][vl] = vals[u];
    __syncthreads();

    int c = t >> 3, vb = (t & 7) * 8;        // 8 threads per channel, 8 v each
    if (v0 + vb < NVOXv) {
        float* o = out + (size_t)b * CC * NVOXv + (size_t)c * NVOXv + v0 + vb;
        float4 w0 = make_float4(tile[c][vb + 0], tile[c][vb + 1], tile[c][vb + 2], tile[c][vb + 3]);
        float4 w1 = make_float4(tile[c][vb + 4], tile[c][vb + 5], tile[c][vb + 6], tile[c][vb + 7]);
        *(float4*)(o)     = w0;
        *(float4*)(o + 4) = w1;
    }
}

// ---------------------------------------------------------------------------
// Kernel 3 (slow): in-place divide where cnt > 1
// ---------------------------------------------------------------------------
__global__ __launch_bounds__(256) void k_mean_slow(
    float* __restrict__ out, const int* __restrict__ cnt)
{
    int v = blockIdx.x * blockDim.x + threadIdx.x;
    if (v >= NVOXv) return;
    int b  = blockIdx.y;
    int c0 = cnt[b * NVOXv + v];
    if (c0 > 1) {
        float cf = (float)c0;
        float* o = out + (size_t)b * CC * NVOXv + v;
#pragma unroll
        for (int c = 0; c < CC; ++c)
            o[(size_t)c * NVOXv] = o[(size_t)c * NVOXv] / cf;
    }
}

// ---------------------------------------------------------------------------
extern "C" void kernel_launch(void* const* d_in, const int* in_sizes, int n_in,
                              void* d_out, int out_size, void* d_ws, size_t ws_size,
                              hipStream_t stream)
{
    const float* fv   = (const float*)d_in[0];
    const float* pim  = (const float*)d_in[1];
    const float* pimf = (const float*)d_in[2];
    const int*   pm   = (const int*)d_in[3];
    const int*   pmf  = (const int*)d_in[4];
    float* out = (float*)d_out;

    const size_t cntB  = (size_t)BB * NVOXv * sizeof(int);        // 1,760,000
    const size_t accB  = (size_t)BB * NVOXv * CC * sizeof(float); // 56,320,000
    const size_t candB = (size_t)BB * NN * sizeof(float4);        //   262,144
    const size_t fvtB  = (size_t)BB * NN * CC * sizeof(float);    // 2,097,152
    const size_t need_fast = 256 + cntB + accB + 2 * candB + fvtB;

    const bool fast = (ws_size >= need_fast);

    char* ws = (char*)d_ws;
    int* ccnt = (int*)ws;                 // BB ints
    int* fcnt = (int*)(ws + 16);          // BB ints
    size_t off = 256;
    int* cnt = (int*)(ws + off); off += cntB;
    float* acc = nullptr;
    size_t zeroBytes;
    if (fast) { acc = (float*)(ws + off); off += accB; zeroBytes = off; }
    else      { zeroBytes = off; }
    float4* cand  = (float4*)(ws + off); off += candB;
    float4* fcand = (float4*)(ws + off); off += candB;
    float* fvT = nullptr;
    if (fast) { fvT = (float*)(ws + off); off += fvtB; }

    hipMemsetAsync(d_ws, 0, zeroBytes, stream);

    dim3 blk(256);
    if (fast) {
        dim3 gt(NN / 64, BB);
        k_tr<<<gt, blk, 0, stream>>>(fv, fvT);

        dim3 g1(NN / 256, BB);
        k_prep<true><<<g1, blk, 0, stream>>>(fv, fvT, pim, pimf, pm, pmf,
                                             acc, cnt, cand, ccnt, fcand, fcnt);
        dim3 g2(NN / FPB, BB);
        k_far<true><<<g2, blk, 0, stream>>>(fv, fvT, cand, ccnt, fcand, fcnt,
                                            acc, cnt);
        dim3 g3((NVOXv + 63) / 64, BB);
        k_mean_fast<<<g3, blk, 0, stream>>>(acc, cnt, out);
    } else {
        hipMemsetAsync(d_out, 0, (size_t)out_size * sizeof(float), stream);

        dim3 g1(NN / 256, BB);
        k_prep<false><<<g1, blk, 0, stream>>>(fv, fvT, pim, pimf, pm, pmf,
                                              out, cnt, cand, ccnt, fcand, fcnt);
        dim3 g2(NN / FPB, BB);
        k_far<false><<<g2, blk, 0, stream>>>(fv, fvT, cand, ccnt, fcand, fcnt,
                                             out, cnt);
        dim3 g3((NVOXv + 255) / 256, BB);
        k_mean_slow<<<g3, blk, 0, stream>>>(out, cnt);
    }
}

// Round 4
// 126.146 us; speedup vs baseline: 1.5129x; 1.2524x over previous
//
#include <hip/hip_runtime.h>

// Problem constants (fixed shapes from setup_inputs / PROJECT_CFG)
#define BB   2
#define CC   32
#define NN   8192               // H*W points per batch
#define N2   (2 * NN)           // near rows [0,NN) + far rows [NN,2NN) in F
#define NXv  440
#define NYv  500
#define NVOXv (NXv * NYv)       // 220000

#define SPLIT 32                // lanes per far point
#define FPB   8                 // far points per 256-thread block

#define INSERT3(dd, jj)                                            \
    if ((dd) < d2) {                                               \
        if ((dd) < d1) {                                           \
            d2 = d1; i2 = i1;                                      \
            if ((dd) < d0) { d1 = d0; i1 = i0; d0 = (dd); i0 = (jj); } \
            else           { d1 = (dd); i1 = (jj); }               \
        } else { d2 = (dd); i2 = (jj); }                           \
    }

// ---------------------------------------------------------------------------
// fv (B,C,N) -> F rows [0,NN): (B,N,C).  Also zeroes the 4 counters.
// ---------------------------------------------------------------------------
__global__ __launch_bounds__(256) void k_tr(
    const float* __restrict__ fv, float* __restrict__ F,
    int* __restrict__ counters)
{
    __shared__ float tile[CC][64 + 1];
    int b  = blockIdx.y;
    int i0 = blockIdx.x * 64;
    int t  = threadIdx.x;
    if (b == 0 && blockIdx.x == 0 && t < 4) counters[t] = 0;

    const float* f = fv + (size_t)b * CC * NN;
    int il = t & 63, cb = t >> 6;            // cb 0..3
#pragma unroll
    for (int p = 0; p < 8; ++p) {
        int c = cb + p * 4;
        tile[c][il] = f[(size_t)c * NN + i0 + il];
    }
    __syncthreads();
    float* o = F + ((size_t)b * N2 + i0) * CC;
    int c2 = t & 31, ib = t >> 5;            // ib 0..7
#pragma unroll
    for (int p = 0; p < 8; ++p) {
        int il2 = ib + p * 8;
        o[(size_t)il2 * CC + c2] = tile[c2][il2];
    }
}

// ---------------------------------------------------------------------------
// Kernel 1: compact near candidates + far actives, chain near points
// ---------------------------------------------------------------------------
__global__ __launch_bounds__(256) void k_prep(
    const float* __restrict__ pim,   // (B,4,N)
    const float* __restrict__ pimf,  // (B,4,N)
    const int*   __restrict__ pm,    // (B,N)
    const int*   __restrict__ pmf,   // (B,N)
    int*         __restrict__ head,  // (B,NVOX), init -1
    int*         __restrict__ nxt,   // (B,2N)
    float4*      __restrict__ cand,  // (B,N)
    int*         __restrict__ ccnt,  // counters[0..1]
    float4*      __restrict__ fcand, // (B,N)
    int*         __restrict__ fcnt)  // counters[2..3]
{
    int b = blockIdx.y;
    int i = blockIdx.x * blockDim.x + threadIdx.x;

    // ---- far point: compact (pmf>0 && in-bounds); store vox in .w ----
    {
        float x = pimf[(b * 4 + 0) * NN + i];
        float y = pimf[(b * 4 + 1) * NN + i];
        float z = pimf[(b * 4 + 2) * NN + i];
        if (pmf[b * NN + i] > 0) {
            int ix = (int)floorf((x - 0.0f)  / 0.16f);
            int iy = (int)floorf((y + 40.0f) / 0.16f);
            if (ix >= 0 && ix < NXv && iy >= 0 && iy < NYv &&
                z >= -3.0f && z < 1.0f) {
                int vox = iy * NXv + ix;
                int pos = atomicAdd(&fcnt[b], 1);
                fcand[b * NN + pos] = make_float4(x, y, z, __int_as_float(vox));
            }
        }
    }

    // ---- near point: candidate list (mask only) + chain (mask & inb) ----
    if (pm[b * NN + i] > 0) {
        float x = pim[(b * 4 + 0) * NN + i];
        float y = pim[(b * 4 + 1) * NN + i];
        float z = pim[(b * 4 + 2) * NN + i];
        int pos = atomicAdd(&ccnt[b], 1);
        cand[b * NN + pos] = make_float4(x, y, z, __int_as_float(i));

        int ix = (int)floorf((x - 0.0f)  / 0.16f);
        int iy = (int)floorf((y + 40.0f) / 0.16f);
        if (ix < 0 || ix >= NXv || iy < 0 || iy >= NYv) return;
        if (!(z >= -3.0f && z < 1.0f)) return;
        int vox = iy * NXv + ix;
        nxt[b * N2 + i] = atomicExch(&head[b * NVOXv + vox], i);
    }
}

// ---------------------------------------------------------------------------
// Kernel 2: far 3-NN + interpolate -> F rows [NN,2NN); chain far points.
// 32 lanes per far point.
// ---------------------------------------------------------------------------
__global__ __launch_bounds__(256) void k_far(
    const float4* __restrict__ cand,
    const int*    __restrict__ ccnt,
    const float4* __restrict__ fcand,
    const int*    __restrict__ fcnt,
    float*        __restrict__ F,     // (B,2N,C)
    int*          __restrict__ head,
    int*          __restrict__ nxt)
{
    int b  = blockIdx.y;
    int nf = fcnt[b];
    int e0 = blockIdx.x * FPB;
    if (e0 >= nf) return;

    int tid = threadIdx.x;
    int sub = tid & (SPLIT - 1);
    int e   = e0 + (tid >> 5);
    if (e >= nf) return;                 // uniform within each 32-lane group

    float4 fp = fcand[b * NN + e];
    float x = fp.x, y = fp.y, z = fp.z;
    int vox = __float_as_int(fp.w);

    int nc = ccnt[b];
    const float4* cb = cand + b * NN;

    float d0 = __builtin_inff(), d1 = __builtin_inff(), d2 = __builtin_inff();
    int   i0 = 0, i1 = 0, i2 = 0;

    int k = sub;
    for (; k + 96 < nc; k += 128) {
        float4 pa = cb[k];
        float4 pb = cb[k + 32];
        float4 pc = cb[k + 64];
        float4 pd = cb[k + 96];
        float dxa = x - pa.x, dya = y - pa.y, dza = z - pa.z;
        float dxb = x - pb.x, dyb = y - pb.y, dzb = z - pb.z;
        float dxc = x - pc.x, dyc = y - pc.y, dzc = z - pc.z;
        float dxd = x - pd.x, dyd = y - pd.y, dzd = z - pd.z;
        float da = dxa * dxa + dya * dya + dza * dza;
        float db = dxb * dxb + dyb * dyb + dzb * dzb;
        float dc = dxc * dxc + dyc * dyc + dzc * dzc;
        float dd = dxd * dxd + dyd * dyd + dzd * dzd;
        int ia = __float_as_int(pa.w);
        int ib = __float_as_int(pb.w);
        int ic = __float_as_int(pc.w);
        int id = __float_as_int(pd.w);
        INSERT3(da, ia);
        INSERT3(db, ib);
        INSERT3(dc, ic);
        INSERT3(dd, id);
    }
    for (; k < nc; k += SPLIT) {
        float4 p = cb[k];
        float dx = x - p.x, dy = y - p.y, dz = z - p.z;
        float d  = dx * dx + dy * dy + dz * dz;
        int  ii  = __float_as_int(p.w);
        INSERT3(d, ii);
    }

    // butterfly merge across the 32-lane group
#pragma unroll
    for (int off = 1; off < SPLIT; off <<= 1) {
        float m0 = __shfl_xor(d0, off), m1 = __shfl_xor(d1, off), m2 = __shfl_xor(d2, off);
        int   g0 = __shfl_xor(i0, off), g1 = __shfl_xor(i1, off), g2 = __shfl_xor(i2, off);
        INSERT3(m0, g0);
        INSERT3(m1, g1);
        INSERT3(m2, g2);
    }

    float r0 = 1.0f / (d0 + 1e-8f);
    float r1 = 1.0f / (d1 + 1e-8f);
    float r2 = 1.0f / (d2 + 1e-8f);
    float s  = r0 + r1 + r2;
    float w0 = r0 / s, w1 = r1 / s, w2 = r2 / s;

    // gather near features (rows < NN of F), write interp row NN+e
    const float* fb = F + ((size_t)b * N2 << 5);
    float v = w0 * fb[((size_t)i0 << 5) + sub] +
              w1 * fb[((size_t)i1 << 5) + sub] +
              w2 * fb[((size_t)i2 << 5) + sub];
    F[(((size_t)b * N2 + NN + e) << 5) + sub] = v;

    if (sub == 0)
        nxt[b * N2 + NN + e] = atomicExch(&head[b * NVOXv + vox], NN + e);
}

// ---------------------------------------------------------------------------
// Kernel 3: per-voxel chain walk -> mean -> transposed out (B,C,NY,NX)
// 64 voxels per block; 4 threads per voxel, 8 channels each.
// ---------------------------------------------------------------------------
__global__ __launch_bounds__(256) void k_final(
    const float* __restrict__ F,     // (B,2N,C)
    const int*   __restrict__ head,  // (B,NVOX)
    const int*   __restrict__ nxt,   // (B,2N)
    float*       __restrict__ out)   // (B,C,NVOX)
{
    __shared__ float tile[CC][64 + 1];
    int b  = blockIdx.y;
    int v0 = blockIdx.x * 64;
    int t  = threadIdx.x;

    int vl = t >> 2, cq = (t & 3) * 8;       // 4 threads per voxel, 8 ch each
    int v  = v0 + vl;
    float acc[8] = {0, 0, 0, 0, 0, 0, 0, 0};
    if (v < NVOXv) {
        int p = head[b * NVOXv + v];
        int n = 0;
        while (p >= 0) {
            const float* f = F + (((size_t)b * N2 + p) << 5) + cq;
            float4 a0 = *(const float4*)f;
            float4 a1 = *(const float4*)(f + 4);
            acc[0] += a0.x; acc[1] += a0.y; acc[2] += a0.z; acc[3] += a0.w;
            acc[4] += a1.x; acc[5] += a1.y; acc[6] += a1.z; acc[7] += a1.w;
            ++n;
            p = nxt[b * N2 + p];
        }
        if (n > 1) {
            float cf = (float)n;
#pragma unroll
            for (int u = 0; u < 8; ++u) acc[u] /= cf;
        }
    }
#pragma unroll
    for (int u = 0; u < 8; ++u) tile[cq + u][vl] = acc[u];
    __syncthreads();

    int c = t >> 3, vb = (t & 7) * 8;        // 8 threads per channel, 8 v each
    if (v0 + vb < NVOXv) {
        float* o = out + (size_t)b * CC * NVOXv + (size_t)c * NVOXv + v0 + vb;
        *(float4*)(o)     = make_float4(tile[c][vb + 0], tile[c][vb + 1],
                                        tile[c][vb + 2], tile[c][vb + 3]);
        *(float4*)(o + 4) = make_float4(tile[c][vb + 4], tile[c][vb + 5],
                                        tile[c][vb + 6], tile[c][vb + 7]);
    }
}

// ---------------------------------------------------------------------------
extern "C" void kernel_launch(void* const* d_in, const int* in_sizes, int n_in,
                              void* d_out, int out_size, void* d_ws, size_t ws_size,
                              hipStream_t stream)
{
    const float* fv   = (const float*)d_in[0];
    const float* pim  = (const float*)d_in[1];
    const float* pimf = (const float*)d_in[2];
    const int*   pm   = (const int*)d_in[3];
    const int*   pmf  = (const int*)d_in[4];
    float* out = (float*)d_out;

    const size_t headB = (size_t)BB * NVOXv * sizeof(int);     // 1,760,000
    const size_t nxtB  = (size_t)BB * N2 * sizeof(int);        //   131,072
    const size_t candB = (size_t)BB * NN * sizeof(float4);     //   524,288
    const size_t FB    = (size_t)BB * N2 * CC * sizeof(float); // 4,194,304

    char* ws = (char*)d_ws;
    int* counters = (int*)ws;             // [ccnt0, ccnt1, fcnt0, fcnt1]
    size_t off = 256;
    int*    head  = (int*)(ws + off);   off += headB;
    int*    nxt   = (int*)(ws + off);   off += nxtB;
    float4* cand  = (float4*)(ws + off); off += candB;
    float4* fcand = (float4*)(ws + off); off += candB;
    float*  F     = (float*)(ws + off);  off += FB;
    (void)ws_size;

    // head = -1 (0xFFFFFFFF); counters zeroed inside k_tr
    hipMemsetAsync(head, 0xFF, headB, stream);

    dim3 blk(256);
    dim3 gt(NN / 64, BB);
    k_tr<<<gt, blk, 0, stream>>>(fv, F, counters);

    dim3 g1(NN / 256, BB);
    k_prep<<<g1, blk, 0, stream>>>(pim, pimf, pm, pmf, head, nxt,
                                   cand, counters, fcand, counters + 2);

    dim3 g2(NN / FPB, BB);
    k_far<<<g2, blk, 0, stream>>>(cand, counters, fcand, counters + 2,
                                  F, head, nxt);

    dim3 g3((NVOXv + 63) / 64, BB);
    k_final<<<g3, blk, 0, stream>>>(F, head, nxt, out);
}